// Round 2
// baseline (3575.087 us; speedup 1.0000x reference)
//
#include <hip/hip_runtime.h>
#include <cstdint>

#define NN 100000
#define EE 1600000
#define ET (EE + NN)

typedef unsigned int u32;

// monotone float->uint mapping so unsigned atomicMax == float max
__device__ __forceinline__ u32 fmap(float f) {
    u32 b = __float_as_uint(f);
    return (b & 0x80000000u) ? ~b : (b | 0x80000000u);
}
__device__ __forceinline__ float funmap(u32 u) {
    u32 b = (u & 0x80000000u) ? (u ^ 0x80000000u) : ~u;
    return __uint_as_float(b);
}
__device__ __forceinline__ void get_edge(const int* __restrict__ ei, int e, int& s, int& d) {
    if (e < EE) { s = ei[e]; d = ei[EE + e]; }
    else { s = e - EE; d = s; }
}
__device__ __forceinline__ float leaky(float x) { return x > 0.f ? x : 0.2f * x; }

// ---------------- GEMM: Hout[N,OUTC] = X[N,128] @ W[128,OUTC]   (all f32)
// block: 32 rows x OUTC cols; thread: TR rows x 4 cols (cols strided by CG)
// NOTE: X may alias Hout — each block reads ALL its 32 rows into LDS before
// writing the same 32 rows; no cross-block row sharing, so this is safe.
template<int OUTC>
__global__ __launch_bounds__(256) void gemm_kernel(
    const float* __restrict__ X, const float* __restrict__ W, float* __restrict__ Hout)
{
    constexpr int CG = OUTC / 4;    // 32 (OUTC=128) or 8 (OUTC=32)
    constexpr int RG = 256 / CG;    // 8 or 32
    constexpr int TR = 32 / RG;     // 4 or 1
    __shared__ float Wt[OUTC * 132];   // [c][k], stride 132
    __shared__ float Xs[32 * 132];     // [r][k], stride 132

    const int tid = threadIdx.x;
    for (int i = tid; i < 128 * OUTC; i += 256) {
        int k = i / OUTC, c = i % OUTC;
        Wt[c * 132 + k] = W[i];
    }
    const int r0 = blockIdx.x * 32;
    {
        const float4* Xg = (const float4*)(X + (size_t)r0 * 128);
        for (int i = tid; i < 32 * 32; i += 256) {
            float4 v = Xg[i];
            int r = i >> 5, kk = (i & 31) << 2;
            *(float4*)&Xs[r * 132 + kk] = v;
        }
    }
    __syncthreads();
    const int cg = tid % CG;
    const int rg = tid / CG;
    float acc[TR][4];
    #pragma unroll
    for (int r = 0; r < TR; r++)
        #pragma unroll
        for (int j = 0; j < 4; j++) acc[r][j] = 0.f;

    for (int k = 0; k < 128; k += 4) {
        float4 xv[TR];
        #pragma unroll
        for (int r = 0; r < TR; r++)
            xv[r] = *(const float4*)&Xs[(rg * TR + r) * 132 + k];
        #pragma unroll
        for (int j = 0; j < 4; j++) {
            const int c = cg + CG * j;
            float4 wv = *(const float4*)&Wt[c * 132 + k];
            #pragma unroll
            for (int r = 0; r < TR; r++)
                acc[r][j] += xv[r].x * wv.x + xv[r].y * wv.y + xv[r].z * wv.z + xv[r].w * wv.w;
        }
    }
    #pragma unroll
    for (int r = 0; r < TR; r++) {
        const size_t row = r0 + rg * TR + r;
        #pragma unroll
        for (int j = 0; j < 4; j++)
            Hout[row * OUTC + cg + CG * j] = acc[r][j];
    }
}

// ---------------- per-node attention coefficients: as[n,h]=h.a_src, ad[n,h]=h.a_dst
template<int H>
__global__ __launch_bounds__(256) void attn_kernel(
    const float* __restrict__ Hb, const float* __restrict__ asw, const float* __restrict__ adw,
    float* __restrict__ as_o, float* __restrict__ ad_o)
{
    int n = blockIdx.x * 256 + threadIdx.x;
    if (n >= NN) return;
    const float4* hp = (const float4*)(Hb + (size_t)n * H * 32);
    float s[H], d[H];
    #pragma unroll
    for (int h = 0; h < H; h++) { s[h] = 0.f; d[h] = 0.f; }
    #pragma unroll
    for (int i = 0; i < H * 8; i++) {
        float4 v = hp[i];
        int h = i >> 3;
        int b = i * 4;
        s[h] += v.x * asw[b] + v.y * asw[b+1] + v.z * asw[b+2] + v.w * asw[b+3];
        d[h] += v.x * adw[b] + v.y * adw[b+1] + v.z * adw[b+2] + v.w * adw[b+3];
    }
    if (H == 4) {
        *(float4*)(as_o + (size_t)n * 4) = make_float4(s[0], s[1], s[2], s[3]);
        *(float4*)(ad_o + (size_t)n * 4) = make_float4(d[0], d[1], d[2], d[3]);
    } else {
        as_o[n] = s[0];
        ad_o[n] = d[0];
    }
}

// ---------------- edge pass 1: segment max of logits into m (mapped uint)
template<int H>
__global__ __launch_bounds__(256) void edge_max_kernel(const int* __restrict__ ei,
    const float* __restrict__ as_, const float* __restrict__ ad_, u32* __restrict__ m)
{
    int e = blockIdx.x * 256 + threadIdx.x;
    if (e >= ET) return;
    int s, d; get_edge(ei, e, s, d);
    #pragma unroll
    for (int h = 0; h < H; h++) {
        float l = leaky(as_[(size_t)s * H + h] + ad_[(size_t)d * H + h]);
        atomicMax(&m[(size_t)d * H + h], fmap(l));
    }
}

// ---------------- edge pass 2: denom[d,h] += exp(logit - m[d,h])
template<int H>
__global__ __launch_bounds__(256) void edge_sum_kernel(const int* __restrict__ ei,
    const float* __restrict__ as_, const float* __restrict__ ad_,
    const u32* __restrict__ m, float* __restrict__ denom)
{
    int e = blockIdx.x * 256 + threadIdx.x;
    if (e >= ET) return;
    int s, d; get_edge(ei, e, s, d);
    #pragma unroll
    for (int h = 0; h < H; h++) {
        float l = leaky(as_[(size_t)s * H + h] + ad_[(size_t)d * H + h]);
        float p = __expf(l - funmap(m[(size_t)d * H + h]));
        atomicAdd(&denom[(size_t)d * H + h], p);
    }
}

// ---------------- edge pass 3: alpha[e,h] = exp(logit - m)/(denom + 1e-16)
template<int H>
__global__ __launch_bounds__(256) void edge_alpha_kernel(const int* __restrict__ ei,
    const float* __restrict__ as_, const float* __restrict__ ad_,
    const u32* __restrict__ m, const float* __restrict__ denom, float* __restrict__ alpha)
{
    int e = blockIdx.x * 256 + threadIdx.x;
    if (e >= ET) return;
    int s, d; get_edge(ei, e, s, d);
    float a[H];
    #pragma unroll
    for (int h = 0; h < H; h++) {
        float l = leaky(as_[(size_t)s * H + h] + ad_[(size_t)d * H + h]);
        float p = __expf(l - funmap(m[(size_t)d * H + h]));
        a[h] = p / (denom[(size_t)d * H + h] + 1e-16f);
    }
    if (H == 4)
        *(float4*)(alpha + (size_t)e * 4) = make_float4(a[0], a[1], a[2], a[3]);
    else
        alpha[e] = a[0];
}

// ---------------- edge pass 4: agg[d,:] += alpha[e,h] * h[s,:]
template<int H>
__global__ __launch_bounds__(256) void scatter_kernel(const int* __restrict__ ei,
    const float* __restrict__ alpha, const float* __restrict__ Hb, float* __restrict__ agg)
{
    constexpr int F = H * 32;
    constexpr int EPB = 256 / F;
    const int t = threadIdx.x;
    const int c = t % F;
    const int e = blockIdx.x * EPB + t / F;
    if (e >= ET) return;
    int s, d; get_edge(ei, e, s, d);
    float a = alpha[(size_t)e * H + (c >> 5)];
    float v = a * Hb[(size_t)s * F + c];
    atomicAdd(&agg[(size_t)d * F + c], v);
}

// ---------------- epilogue: out = (elu?)(agg + b), f32
template<int F, bool DOELU>
__global__ __launch_bounds__(256) void bias_act_kernel(const float* __restrict__ agg,
    const float* __restrict__ b, float* __restrict__ outp)
{
    size_t idx = (size_t)blockIdx.x * 256 + threadIdx.x;
    if (idx >= (size_t)NN * F) return;
    int c = idx % F;
    float v = agg[idx] + b[c];
    if (DOELU) v = v > 0.f ? v : (__expf(v) - 1.f);
    outp[idx] = v;
}

extern "C" void kernel_launch(void* const* d_in, const int* in_sizes, int n_in,
                              void* d_out, int out_size, void* d_ws, size_t ws_size,
                              hipStream_t stream)
{
    const float* x   = (const float*)d_in[0];
    const int*   ei  = (const int*)d_in[1];
    const float* W1  = (const float*)d_in[2];
    const float* as1 = (const float*)d_in[3];
    const float* ad1 = (const float*)d_in[4];
    const float* b1  = (const float*)d_in[5];
    const float* W2  = (const float*)d_in[6];
    const float* as2 = (const float*)d_in[7];
    const float* ad2 = (const float*)d_in[8];
    const float* b2  = (const float*)d_in[9];
    const float* W3  = (const float*)d_in[10];
    const float* as3 = (const float*)d_in[11];
    const float* ad3 = (const float*)d_in[12];
    const float* b3  = (const float*)d_in[13];
    float* outp = (float*)d_out;

    char* ws = (char*)d_ws;
    // A region: agg (N*128 f32 for layers 1/2). Layer 3: agg3 at A+0 (N*32 f32),
    //           h3 at A+12.8MB (N*32 f32) — layer-2 agg is dead by then.
    float* agg  = (float*)(ws);                  // 51.2 MB
    float* h3   = (float*)(ws + 12800000);       // layer-3 h (N*32 f32), inside A
    // B region: h for layers 1/2 AND next-layer input x2 (aliased — safe, see gemm note)
    float* hbuf = (float*)(ws + 51200000);       // 51.2 MB
    float* asb  = (float*)(ws + 102400000);      // N*4 f32 = 1.6 MB
    float* adb  = (float*)(ws + 104000000);      // 1.6 MB
    u32*   mb   = (u32*)(ws + 105600000);        // 1.6 MB
    float* denb = (float*)(ws + 107200000);      // 1.6 MB
    float* alb  = (float*)(ws + 108800000);      // (E+N)*4 f32 = 27.2 MB -> total 136 MB

    const dim3 B(256);
    const int gN = (NN + 255) / 256;
    const int gE = (ET + 255) / 256;
    const int gG = NN / 32;          // 3125, exact

    // ---------------- layer 1 (H=4)
    hipMemsetAsync(agg, 0, (size_t)NN * 128 * 4, stream);
    hipMemsetAsync(mb, 0, (size_t)NN * 4 * 4, stream);
    hipMemsetAsync(denb, 0, (size_t)NN * 4 * 4, stream);
    gemm_kernel<128><<<gG, B, 0, stream>>>(x, W1, hbuf);
    attn_kernel<4><<<gN, B, 0, stream>>>(hbuf, as1, ad1, asb, adb);
    edge_max_kernel<4><<<gE, B, 0, stream>>>(ei, asb, adb, mb);
    edge_sum_kernel<4><<<gE, B, 0, stream>>>(ei, asb, adb, mb, denb);
    edge_alpha_kernel<4><<<gE, B, 0, stream>>>(ei, asb, adb, mb, denb, alb);
    scatter_kernel<4><<<(ET + 1) / 2, B, 0, stream>>>(ei, alb, hbuf, agg);
    bias_act_kernel<128, true><<<(NN * 128) / 256, B, 0, stream>>>(agg, b1, hbuf);

    // ---------------- layer 2 (H=4)  (x2 == hbuf)
    hipMemsetAsync(agg, 0, (size_t)NN * 128 * 4, stream);
    hipMemsetAsync(mb, 0, (size_t)NN * 4 * 4, stream);
    hipMemsetAsync(denb, 0, (size_t)NN * 4 * 4, stream);
    gemm_kernel<128><<<gG, B, 0, stream>>>(hbuf, W2, hbuf);
    attn_kernel<4><<<gN, B, 0, stream>>>(hbuf, as2, ad2, asb, adb);
    edge_max_kernel<4><<<gE, B, 0, stream>>>(ei, asb, adb, mb);
    edge_sum_kernel<4><<<gE, B, 0, stream>>>(ei, asb, adb, mb, denb);
    edge_alpha_kernel<4><<<gE, B, 0, stream>>>(ei, asb, adb, mb, denb, alb);
    scatter_kernel<4><<<(ET + 1) / 2, B, 0, stream>>>(ei, alb, hbuf, agg);
    bias_act_kernel<128, true><<<(NN * 128) / 256, B, 0, stream>>>(agg, b2, hbuf);

    // ---------------- layer 3 (H=1, C=32)
    hipMemsetAsync(mb, 0, (size_t)NN * 4, stream);
    hipMemsetAsync(denb, 0, (size_t)NN * 4, stream);
    gemm_kernel<32><<<gG, B, 0, stream>>>(hbuf, W3, h3);
    hipMemsetAsync(agg, 0, (size_t)NN * 32 * 4, stream);
    attn_kernel<1><<<gN, B, 0, stream>>>(h3, as3, ad3, asb, adb);
    edge_max_kernel<1><<<gE, B, 0, stream>>>(ei, asb, adb, mb);
    edge_sum_kernel<1><<<gE, B, 0, stream>>>(ei, asb, adb, mb, denb);
    edge_alpha_kernel<1><<<gE, B, 0, stream>>>(ei, asb, adb, mb, denb, alb);
    scatter_kernel<1><<<(ET + 7) / 8, B, 0, stream>>>(ei, alb, h3, agg);
    bias_act_kernel<32, false><<<(NN * 32) / 256, B, 0, stream>>>(agg, b3, outp);
}

// Round 3
// 1389.400 us; speedup vs baseline: 2.5731x; 2.5731x over previous
//
#include <hip/hip_runtime.h>
#include <cstdint>

#define NN 100000
#define EE 1600000
#define ET (EE + NN)
#define NB_SCAN 98            // ceil(NN/1024)

typedef unsigned int u32;

__device__ __forceinline__ void get_edge(const int* __restrict__ ei, int e, int& s, int& d) {
    if (e < EE) { s = ei[e]; d = ei[EE + e]; }
    else { s = e - EE; d = s; }
}
__device__ __forceinline__ float leaky(float x) { return x > 0.f ? x : 0.2f * x; }

// ---------------- GEMM: Hout[N,OUTC] = X[N,128] @ W[128,OUTC]   (all f32)
template<int OUTC>
__global__ __launch_bounds__(256) void gemm_kernel(
    const float* __restrict__ X, const float* __restrict__ W, float* __restrict__ Hout)
{
    constexpr int CG = OUTC / 4;
    constexpr int RG = 256 / CG;
    constexpr int TR = 32 / RG;
    __shared__ float Wt[OUTC * 132];   // [c][k]
    __shared__ float Xs[32 * 132];     // [r][k]

    const int tid = threadIdx.x;
    for (int i = tid; i < 128 * OUTC; i += 256) {
        int k = i / OUTC, c = i % OUTC;
        Wt[c * 132 + k] = W[i];
    }
    const int r0 = blockIdx.x * 32;
    {
        const float4* Xg = (const float4*)(X + (size_t)r0 * 128);
        for (int i = tid; i < 32 * 32; i += 256) {
            float4 v = Xg[i];
            int r = i >> 5, kk = (i & 31) << 2;
            *(float4*)&Xs[r * 132 + kk] = v;
        }
    }
    __syncthreads();
    const int cg = tid % CG;
    const int rg = tid / CG;
    float acc[TR][4];
    #pragma unroll
    for (int r = 0; r < TR; r++)
        #pragma unroll
        for (int j = 0; j < 4; j++) acc[r][j] = 0.f;

    for (int k = 0; k < 128; k += 4) {
        float4 xv[TR];
        #pragma unroll
        for (int r = 0; r < TR; r++)
            xv[r] = *(const float4*)&Xs[(rg * TR + r) * 132 + k];
        #pragma unroll
        for (int j = 0; j < 4; j++) {
            const int c = cg + CG * j;
            float4 wv = *(const float4*)&Wt[c * 132 + k];
            #pragma unroll
            for (int r = 0; r < TR; r++)
                acc[r][j] += xv[r].x * wv.x + xv[r].y * wv.y + xv[r].z * wv.z + xv[r].w * wv.w;
        }
    }
    #pragma unroll
    for (int r = 0; r < TR; r++) {
        const size_t row = r0 + rg * TR + r;
        #pragma unroll
        for (int j = 0; j < 4; j++)
            Hout[row * OUTC + cg + CG * j] = acc[r][j];
    }
}

// ---------------- per-node attention coefficients
template<int H>
__global__ __launch_bounds__(256) void attn_kernel(
    const float* __restrict__ Hb, const float* __restrict__ asw, const float* __restrict__ adw,
    float* __restrict__ as_o, float* __restrict__ ad_o)
{
    int n = blockIdx.x * 256 + threadIdx.x;
    if (n >= NN) return;
    const float4* hp = (const float4*)(Hb + (size_t)n * H * 32);
    float s[H], d[H];
    #pragma unroll
    for (int h = 0; h < H; h++) { s[h] = 0.f; d[h] = 0.f; }
    #pragma unroll
    for (int i = 0; i < H * 8; i++) {
        float4 v = hp[i];
        int h = i >> 3;
        int b = i * 4;
        s[h] += v.x * asw[b] + v.y * asw[b+1] + v.z * asw[b+2] + v.w * asw[b+3];
        d[h] += v.x * adw[b] + v.y * adw[b+1] + v.z * adw[b+2] + v.w * adw[b+3];
    }
    if (H == 4) {
        *(float4*)(as_o + (size_t)n * 4) = make_float4(s[0], s[1], s[2], s[3]);
        *(float4*)(ad_o + (size_t)n * 4) = make_float4(d[0], d[1], d[2], d[3]);
    } else {
        as_o[n] = s[0];
        ad_o[n] = d[0];
    }
}

// ---------------- CSR build ----------------
__global__ __launch_bounds__(256) void count_kernel(const int* __restrict__ ei, int* __restrict__ deg)
{
    int e = blockIdx.x * 256 + threadIdx.x;
    if (e >= ET) return;
    int s, d; get_edge(ei, e, s, d);
    atomicAdd(&deg[d], 1);
}

// per-block exclusive scan of 1024 elements (256 thr x 4), block totals out
__global__ __launch_bounds__(256) void scan1_kernel(const int* __restrict__ deg,
    int* __restrict__ rowp, int* __restrict__ bsum)
{
    __shared__ int lds[256];
    const int t = threadIdx.x;
    const int base = blockIdx.x * 1024 + t * 4;
    int v0 = (base + 0 < NN) ? deg[base + 0] : 0;
    int v1 = (base + 1 < NN) ? deg[base + 1] : 0;
    int v2 = (base + 2 < NN) ? deg[base + 2] : 0;
    int v3 = (base + 3 < NN) ? deg[base + 3] : 0;
    int local = v0 + v1 + v2 + v3;
    lds[t] = local;
    __syncthreads();
    for (int off = 1; off < 256; off <<= 1) {
        int x = (t >= off) ? lds[t - off] : 0;
        __syncthreads();
        lds[t] += x;
        __syncthreads();
    }
    int excl = lds[t] - local;
    if (base + 0 < NN) rowp[base + 0] = excl;
    if (base + 1 < NN) rowp[base + 1] = excl + v0;
    if (base + 2 < NN) rowp[base + 2] = excl + v0 + v1;
    if (base + 3 < NN) rowp[base + 3] = excl + v0 + v1 + v2;
    if (t == 255) bsum[blockIdx.x] = lds[255];
}

// single block: exclusive scan of the 98 block sums (in place)
__global__ __launch_bounds__(128) void scan2_kernel(int* __restrict__ bsum)
{
    __shared__ int lds[128];
    const int t = threadIdx.x;
    int v = (t < NB_SCAN) ? bsum[t] : 0;
    lds[t] = v;
    __syncthreads();
    for (int off = 1; off < 128; off <<= 1) {
        int x = (t >= off) ? lds[t - off] : 0;
        __syncthreads();
        lds[t] += x;
        __syncthreads();
    }
    if (t < NB_SCAN) bsum[t] = lds[t] - v;
}

__global__ __launch_bounds__(256) void scan3_kernel(int* __restrict__ rowp,
    const int* __restrict__ bsum, int* __restrict__ cursor)
{
    int i = blockIdx.x * 256 + threadIdx.x;
    if (i == 0) rowp[NN] = ET;   // will be overwritten below only if NN<grid... NN slot set here
    if (i >= NN) return;
    int r = rowp[i] + bsum[i >> 10];
    rowp[i] = r;
    cursor[i] = r;
}

__global__ __launch_bounds__(256) void fill_kernel(const int* __restrict__ ei,
    int* __restrict__ cursor, int* __restrict__ col)
{
    int e = blockIdx.x * 256 + threadIdx.x;
    if (e >= ET) return;
    int s, d; get_edge(ei, e, s, d);
    int pos = atomicAdd(&cursor[d], 1);
    col[pos] = s;
}

// ---------------- fused segment-softmax + aggregation + bias(+ELU), no atomics
// F = H*32 threads per node; 32-thread group per head does max/denom reduction,
// then all F threads walk the edge list accumulating alpha * h[src][c].
template<int H, bool DOELU>
__global__ __launch_bounds__(256) void agg_csr_kernel(
    const int* __restrict__ rowp, const int* __restrict__ col,
    const float* __restrict__ as_, const float* __restrict__ ad_,
    const float* __restrict__ Hb, const float* __restrict__ bias,
    float* __restrict__ outp)
{
    constexpr int F = H * 32;
    constexpr int NPB = 256 / F;
    const int t = threadIdx.x;
    const int node = blockIdx.x * NPB + t / F;
    const int c = t % F;
    const int h = c >> 5;
    const int lane = c & 31;

    const int start = rowp[node];
    const int end   = rowp[node + 1];
    const float adv = ad_[(size_t)node * H + h];

    // phase 1: segment max (per head, 32 lanes strided)
    float m = -1e30f;
    for (int j = start + lane; j < end; j += 32) {
        int s = col[j];
        float l = leaky(as_[(size_t)s * H + h] + adv);
        m = fmaxf(m, l);
    }
    #pragma unroll
    for (int off = 16; off; off >>= 1) m = fmaxf(m, __shfl_xor(m, off, 32));

    // phase 2: denom
    float den = 0.f;
    for (int j = start + lane; j < end; j += 32) {
        int s = col[j];
        float l = leaky(as_[(size_t)s * H + h] + adv);
        den += __expf(l - m);
    }
    #pragma unroll
    for (int off = 16; off; off >>= 1) den += __shfl_xor(den, off, 32);
    const float rden = 1.f / (den + 1e-16f);

    // phase 3: weighted gather, all F threads per edge
    float acc = 0.f;
    for (int j = start; j < end; j++) {
        int s = col[j];
        float l = leaky(as_[(size_t)s * H + h] + adv);
        float a = __expf(l - m) * rden;
        acc += a * Hb[(size_t)s * F + c];
    }
    float v = acc + bias[c];
    if (DOELU) v = v > 0.f ? v : (__expf(v) - 1.f);
    outp[(size_t)node * F + c] = v;
}

extern "C" void kernel_launch(void* const* d_in, const int* in_sizes, int n_in,
                              void* d_out, int out_size, void* d_ws, size_t ws_size,
                              hipStream_t stream)
{
    const float* x   = (const float*)d_in[0];
    const int*   ei  = (const int*)d_in[1];
    const float* W1  = (const float*)d_in[2];
    const float* as1 = (const float*)d_in[3];
    const float* ad1 = (const float*)d_in[4];
    const float* b1  = (const float*)d_in[5];
    const float* W2  = (const float*)d_in[6];
    const float* as2 = (const float*)d_in[7];
    const float* ad2 = (const float*)d_in[8];
    const float* b2  = (const float*)d_in[9];
    const float* W3  = (const float*)d_in[10];
    const float* as3 = (const float*)d_in[11];
    const float* ad3 = (const float*)d_in[12];
    const float* b3  = (const float*)d_in[13];
    float* outp = (float*)d_out;

    char* ws = (char*)d_ws;
    float* hbuf  = (float*)(ws);                  // N*128 f32 = 51.2 MB (gemm out)
    float* xbuf  = (float*)(ws + 51200000);       // N*128 f32 = 51.2 MB (agg out / next in)
    float* h3    = (float*)(ws + 102400000);      // N*32 f32 = 12.8 MB
    float* asb   = (float*)(ws + 115200000);      // N*4 f32
    float* adb   = (float*)(ws + 116800000);      // N*4 f32
    int*   deg   = (int*)(ws + 118400000);        // N ints
    int*   rowp  = (int*)(ws + 118800000);        // N+1 ints
    int*   cursor= (int*)(ws + 119200016);        // N ints
    int*   col   = (int*)(ws + 119600032);        // ET ints = 6.8 MB
    int*   bsum  = (int*)(ws + 126400032);        // 98 ints   -> total ~126.4 MB

    const dim3 B(256);
    const int gN = (NN + 255) / 256;
    const int gE = (ET + 255) / 256;
    const int gG = NN / 32;

    // ---------------- CSR build (edge structure shared by all layers)
    hipMemsetAsync(deg, 0, (size_t)NN * 4, stream);
    count_kernel<<<gE, B, 0, stream>>>(ei, deg);
    scan1_kernel<<<NB_SCAN, B, 0, stream>>>(deg, rowp, bsum);
    scan2_kernel<<<1, dim3(128), 0, stream>>>(bsum);
    scan3_kernel<<<gN, B, 0, stream>>>(rowp, bsum, cursor);
    fill_kernel<<<gE, B, 0, stream>>>(ei, cursor, col);

    // ---------------- layer 1 (H=4)
    gemm_kernel<128><<<gG, B, 0, stream>>>(x, W1, hbuf);
    attn_kernel<4><<<gN, B, 0, stream>>>(hbuf, as1, ad1, asb, adb);
    agg_csr_kernel<4, true><<<NN / 2, B, 0, stream>>>(rowp, col, asb, adb, hbuf, b1, xbuf);

    // ---------------- layer 2 (H=4)
    gemm_kernel<128><<<gG, B, 0, stream>>>(xbuf, W2, hbuf);
    attn_kernel<4><<<gN, B, 0, stream>>>(hbuf, as2, ad2, asb, adb);
    agg_csr_kernel<4, true><<<NN / 2, B, 0, stream>>>(rowp, col, asb, adb, hbuf, b2, xbuf);

    // ---------------- layer 3 (H=1, C=32)
    gemm_kernel<32><<<gG, B, 0, stream>>>(xbuf, W3, h3);
    attn_kernel<1><<<gN, B, 0, stream>>>(h3, as3, ad3, asb, adb);
    agg_csr_kernel<1, false><<<NN / 8, B, 0, stream>>>(rowp, col, asb, adb, h3, b3, outp);
}

// Round 4
// 1030.983 us; speedup vs baseline: 3.4676x; 1.3476x over previous
//
#include <hip/hip_runtime.h>
#include <cstdint>

#define NN 100000
#define EE 1600000
#define ET (EE + NN)
#define NB_SCAN 98            // ceil(NN/1024)

typedef unsigned int u32;
typedef unsigned short u16;

__device__ __forceinline__ u16 f2bf(float f) {
    union { float f; u32 i; } v; v.f = f;
    u32 r = v.i + 0x7FFFu + ((v.i >> 16) & 1u);
    return (u16)(r >> 16);
}
__device__ __forceinline__ float bf2f(u16 u) {
    union { u32 i; float f; } v; v.i = ((u32)u) << 16; return v.f;
}
__device__ __forceinline__ void get_edge(const int* __restrict__ ei, int e, int& s, int& d) {
    if (e < EE) { s = ei[e]; d = ei[EE + e]; }
    else { s = e - EE; d = s; }
}
__device__ __forceinline__ float leaky(float x) { return x > 0.f ? x : 0.2f * x; }

// ---------------- GEMM: Hout[N,OUTC] = X[N,128] @ W[128,OUTC]  (f32 in, f32+bf16 out)
// 64 rows x OUTC cols per block, 256 threads. W staged per-32-k chunk in [k][c]
// layout (conflict-free b32 LDS reads). X rows staged once (broadcast reads).
// X may alias Hout: block stages all 64 input rows before any store.
template<int OUTC>
__global__ __launch_bounds__(256) void gemm_kernel(
    const float* __restrict__ X, const float* __restrict__ W,
    float* __restrict__ Hout, u16* __restrict__ Hout16)
{
    constexpr int CG = OUTC / 4;     // 32 or 8
    constexpr int RG = 256 / CG;     // 8 or 32
    constexpr int TR = 64 / RG;      // 8 or 2
    __shared__ float Xs[64 * 132];   // 33.8 KB
    __shared__ float Wt[32 * OUTC];  // 16 KB (128) / 4 KB (32), [k][c]

    const int tid = threadIdx.x;
    const int r0 = blockIdx.x * 64;
    for (int i = tid; i < 64 * 32; i += 256) {
        int r = i >> 5, kk = (i & 31) << 2;
        float4 v = make_float4(0.f, 0.f, 0.f, 0.f);
        if (r0 + r < NN) v = *(const float4*)(X + (size_t)(r0 + r) * 128 + kk);
        *(float4*)&Xs[r * 132 + kk] = v;
    }
    const int cg = tid % CG;
    const int rg = tid / CG;
    float acc[TR][4];
    #pragma unroll
    for (int r = 0; r < TR; r++)
        #pragma unroll
        for (int j = 0; j < 4; j++) acc[r][j] = 0.f;

    for (int kc = 0; kc < 4; kc++) {
        __syncthreads();
        for (int i = tid; i < 32 * OUTC / 4; i += 256)
            *(float4*)&Wt[i * 4] = *(const float4*)(W + kc * 32 * OUTC + i * 4);
        __syncthreads();
        #pragma unroll
        for (int k0 = 0; k0 < 32; k0 += 4) {
            float4 xv[TR];
            #pragma unroll
            for (int r = 0; r < TR; r++)
                xv[r] = *(const float4*)&Xs[(rg * TR + r) * 132 + kc * 32 + k0];
            #pragma unroll
            for (int j = 0; j < 4; j++) {
                const int c = cg + CG * j;
                float w0 = Wt[(k0 + 0) * OUTC + c];
                float w1 = Wt[(k0 + 1) * OUTC + c];
                float w2 = Wt[(k0 + 2) * OUTC + c];
                float w3 = Wt[(k0 + 3) * OUTC + c];
                #pragma unroll
                for (int r = 0; r < TR; r++)
                    acc[r][j] += xv[r].x * w0 + xv[r].y * w1 + xv[r].z * w2 + xv[r].w * w3;
            }
        }
    }
    #pragma unroll
    for (int r = 0; r < TR; r++) {
        const int row = r0 + rg * TR + r;
        if (row < NN) {
            #pragma unroll
            for (int j = 0; j < 4; j++) {
                float v = acc[r][j];
                Hout[(size_t)row * OUTC + cg + CG * j] = v;
                Hout16[(size_t)row * OUTC + cg + CG * j] = f2bf(v);
            }
        }
    }
}

// ---------------- per-node attention coefficients (reads fp32 h — exact logits)
template<int H>
__global__ __launch_bounds__(256) void attn_kernel(
    const float* __restrict__ Hb, const float* __restrict__ asw, const float* __restrict__ adw,
    float* __restrict__ as_o, float* __restrict__ ad_o)
{
    int n = blockIdx.x * 256 + threadIdx.x;
    if (n >= NN) return;
    const float4* hp = (const float4*)(Hb + (size_t)n * H * 32);
    float s[H], d[H];
    #pragma unroll
    for (int h = 0; h < H; h++) { s[h] = 0.f; d[h] = 0.f; }
    #pragma unroll
    for (int i = 0; i < H * 8; i++) {
        float4 v = hp[i];
        int h = i >> 3;
        int b = i * 4;
        s[h] += v.x * asw[b] + v.y * asw[b+1] + v.z * asw[b+2] + v.w * asw[b+3];
        d[h] += v.x * adw[b] + v.y * adw[b+1] + v.z * adw[b+2] + v.w * adw[b+3];
    }
    if (H == 4) {
        *(float4*)(as_o + (size_t)n * 4) = make_float4(s[0], s[1], s[2], s[3]);
        *(float4*)(ad_o + (size_t)n * 4) = make_float4(d[0], d[1], d[2], d[3]);
    } else {
        as_o[n] = s[0];
        ad_o[n] = d[0];
    }
}

// ---------------- CSR build ----------------
__global__ __launch_bounds__(256) void count_kernel(const int* __restrict__ ei, int* __restrict__ deg)
{
    int e = blockIdx.x * 256 + threadIdx.x;
    if (e >= ET) return;
    int s, d; get_edge(ei, e, s, d);
    atomicAdd(&deg[d], 1);
}

__global__ __launch_bounds__(256) void scan1_kernel(const int* __restrict__ deg,
    int* __restrict__ rowp, int* __restrict__ bsum)
{
    __shared__ int lds[256];
    const int t = threadIdx.x;
    const int base = blockIdx.x * 1024 + t * 4;
    int v0 = (base + 0 < NN) ? deg[base + 0] : 0;
    int v1 = (base + 1 < NN) ? deg[base + 1] : 0;
    int v2 = (base + 2 < NN) ? deg[base + 2] : 0;
    int v3 = (base + 3 < NN) ? deg[base + 3] : 0;
    int local = v0 + v1 + v2 + v3;
    lds[t] = local;
    __syncthreads();
    for (int off = 1; off < 256; off <<= 1) {
        int x = (t >= off) ? lds[t - off] : 0;
        __syncthreads();
        lds[t] += x;
        __syncthreads();
    }
    int excl = lds[t] - local;
    if (base + 0 < NN) rowp[base + 0] = excl;
    if (base + 1 < NN) rowp[base + 1] = excl + v0;
    if (base + 2 < NN) rowp[base + 2] = excl + v0 + v1;
    if (base + 3 < NN) rowp[base + 3] = excl + v0 + v1 + v2;
    if (t == 255) bsum[blockIdx.x] = lds[255];
}

__global__ __launch_bounds__(128) void scan2_kernel(int* __restrict__ bsum)
{
    __shared__ int lds[128];
    const int t = threadIdx.x;
    int v = (t < NB_SCAN) ? bsum[t] : 0;
    lds[t] = v;
    __syncthreads();
    for (int off = 1; off < 128; off <<= 1) {
        int x = (t >= off) ? lds[t - off] : 0;
        __syncthreads();
        lds[t] += x;
        __syncthreads();
    }
    if (t < NB_SCAN) bsum[t] = lds[t] - v;
}

__global__ __launch_bounds__(256) void scan3_kernel(int* __restrict__ rowp,
    const int* __restrict__ bsum, int* __restrict__ cursor)
{
    int i = blockIdx.x * 256 + threadIdx.x;
    if (i == 0) rowp[NN] = ET;
    if (i >= NN) return;
    int r = rowp[i] + bsum[i >> 10];
    rowp[i] = r;
    cursor[i] = r;
}

__global__ __launch_bounds__(256) void fill_kernel(const int* __restrict__ ei,
    int* __restrict__ cursor, int* __restrict__ col)
{
    int e = blockIdx.x * 256 + threadIdx.x;
    if (e >= ET) return;
    int s, d; get_edge(ei, e, s, d);
    int pos = atomicAdd(&cursor[d], 1);
    col[pos] = s;
}

// ---------------- fused single-pass online-softmax aggregation
// F = H*32 threads per node. Per 32-lane head-group: lane k computes logit/exp for
// edge j0+k (once!), chunk max + denom via shuffle reduce, then inner loop
// broadcasts (p, row-offset) via __shfl while every thread gathers its bf16 channel.
template<int H, bool DOELU>
__global__ __launch_bounds__(256) void agg_csr_kernel(
    const int* __restrict__ rowp, const int* __restrict__ col,
    const float* __restrict__ as_, const float* __restrict__ ad_,
    const u16* __restrict__ Hb16, const float* __restrict__ bias,
    float* __restrict__ outp)
{
    constexpr int F = H * 32;
    constexpr int NPB = 256 / F;
    const int t = threadIdx.x;
    const int node = blockIdx.x * NPB + t / F;
    const int c = t % F;
    const int h = c >> 5;
    const int lane = c & 31;

    const int start = rowp[node];
    const int end   = rowp[node + 1];
    const float adv = ad_[(size_t)node * H + h];
    const char* hbase = (const char*)Hb16 + (size_t)c * 2;

    float m = -1e30f, den = 0.f, acc = 0.f;
    for (int j0 = start; j0 < end; j0 += 32) {
        const int j = j0 + lane;
        const bool valid = (j < end);
        const int s = valid ? col[j] : 0;
        float l = valid ? leaky(as_[(size_t)s * H + h] + adv) : -1e30f;
        // chunk max
        float cm = l;
        #pragma unroll
        for (int off = 16; off; off >>= 1) cm = fmaxf(cm, __shfl_xor(cm, off, 32));
        const float mnew = fmaxf(m, cm);
        const float scale = __expf(m - mnew);
        acc *= scale; den *= scale;
        m = mnew;
        const float p = valid ? __expf(l - m) : 0.f;
        float ps = p;
        #pragma unroll
        for (int off = 16; off; off >>= 1) ps += __shfl_xor(ps, off, 32);
        den += ps;
        const int soff = s * (F * 2);   // byte offset of source row
        int cnt = end - j0; if (cnt > 32) cnt = 32;
        for (int i = 0; i < cnt; i++) {
            const float pi = __shfl(p, i, 32);
            const int so = __shfl(soff, i, 32);
            acc += pi * bf2f(*(const u16*)(hbase + so));
        }
    }
    float v = acc / (den + 1e-16f) + bias[c];
    if (DOELU) v = v > 0.f ? v : (__expf(v) - 1.f);
    outp[(size_t)node * F + c] = v;
}

extern "C" void kernel_launch(void* const* d_in, const int* in_sizes, int n_in,
                              void* d_out, int out_size, void* d_ws, size_t ws_size,
                              hipStream_t stream)
{
    const float* x   = (const float*)d_in[0];
    const int*   ei  = (const int*)d_in[1];
    const float* W1  = (const float*)d_in[2];
    const float* as1 = (const float*)d_in[3];
    const float* ad1 = (const float*)d_in[4];
    const float* b1  = (const float*)d_in[5];
    const float* W2  = (const float*)d_in[6];
    const float* as2 = (const float*)d_in[7];
    const float* ad2 = (const float*)d_in[8];
    const float* b2  = (const float*)d_in[9];
    const float* W3  = (const float*)d_in[10];
    const float* as3 = (const float*)d_in[11];
    const float* ad3 = (const float*)d_in[12];
    const float* b3  = (const float*)d_in[13];
    float* outp = (float*)d_out;

    char* ws = (char*)d_ws;
    float* hbuf  = (float*)(ws);                  // N*128 f32 = 51.2 MB (h, then agg-out/next-in)
    u16*   hb16  = (u16*)(ws + 51300000);         // N*128 bf16 = 25.6 MB (gather copy)
    float* h3    = (float*)(ws + 77000000);       // N*32 f32 = 12.8 MB
    u16*   h3b16 = (u16*)(ws + 89900000);         // N*32 bf16 = 6.4 MB
    float* asb   = (float*)(ws + 96400000);       // N*4 f32
    float* adb   = (float*)(ws + 98000000);       // N*4 f32
    int*   deg   = (int*)(ws + 99600000);
    int*   rowp  = (int*)(ws + 100000000);
    int*   cursor= (int*)(ws + 100400016);
    int*   col   = (int*)(ws + 100800016);        // 6.8 MB
    int*   bsum  = (int*)(ws + 107600016);        // total ~107.6 MB

    const dim3 B(256);
    const int gN = (NN + 255) / 256;
    const int gE = (ET + 255) / 256;
    const int gG = (NN + 63) / 64;   // 1563

    // ---------------- CSR build (shared by all layers)
    hipMemsetAsync(deg, 0, (size_t)NN * 4, stream);
    count_kernel<<<gE, B, 0, stream>>>(ei, deg);
    scan1_kernel<<<NB_SCAN, B, 0, stream>>>(deg, rowp, bsum);
    scan2_kernel<<<1, dim3(128), 0, stream>>>(bsum);
    scan3_kernel<<<gN, B, 0, stream>>>(rowp, bsum, cursor);
    fill_kernel<<<gE, B, 0, stream>>>(ei, cursor, col);

    // ---------------- layer 1 (H=4)
    gemm_kernel<128><<<gG, B, 0, stream>>>(x, W1, hbuf, hb16);
    attn_kernel<4><<<gN, B, 0, stream>>>(hbuf, as1, ad1, asb, adb);
    agg_csr_kernel<4, true><<<NN / 2, B, 0, stream>>>(rowp, col, asb, adb, hb16, b1, hbuf);

    // ---------------- layer 2 (H=4)
    gemm_kernel<128><<<gG, B, 0, stream>>>(hbuf, W2, hbuf, hb16);
    attn_kernel<4><<<gN, B, 0, stream>>>(hbuf, as2, ad2, asb, adb);
    agg_csr_kernel<4, true><<<NN / 2, B, 0, stream>>>(rowp, col, asb, adb, hb16, b2, hbuf);

    // ---------------- layer 3 (H=1, C=32)
    gemm_kernel<32><<<gG, B, 0, stream>>>(hbuf, W3, h3, h3b16);
    attn_kernel<1><<<gN, B, 0, stream>>>(h3, as3, ad3, asb, adb);
    agg_csr_kernel<1, false><<<NN / 8, B, 0, stream>>>(rowp, col, asb, adb, h3b16, b3, outp);
}

// Round 5
// 901.518 us; speedup vs baseline: 3.9656x; 1.1436x over previous
//
#include <hip/hip_runtime.h>
#include <cstdint>

#define NN 100000
#define EE 1600000
#define ET (EE + NN)
#define NB_SCAN 98            // ceil(NN/1024)

typedef unsigned int u32;
typedef unsigned short u16;

__device__ __forceinline__ u16 f2bf(float f) {
    union { float f; u32 i; } v; v.f = f;
    u32 r = v.i + 0x7FFFu + ((v.i >> 16) & 1u);
    return (u16)(r >> 16);
}
__device__ __forceinline__ float bf2f(u32 u) {
    union { u32 i; float f; } v; v.i = u << 16; return v.f;
}
__device__ __forceinline__ void get_edge(const int* __restrict__ ei, int e, int& s, int& d) {
    if (e < EE) { s = ei[e]; d = ei[EE + e]; }
    else { s = e - EE; d = s; }
}
__device__ __forceinline__ float leaky(float x) { return x > 0.f ? x : 0.2f * x; }

// ---------------- GEMM + fused attn epilogue.
// Hout16[N,OUTC] (bf16) = X[N,128] @ W[128,OUTC]; as/ad from fp32 accumulators.
// 64 rows x OUTC per block, 256 threads. No fp32 h is ever written.
template<int OUTC>
__global__ __launch_bounds__(256) void gemm_kernel(
    const float* __restrict__ X, const float* __restrict__ W,
    const float* __restrict__ asw, const float* __restrict__ adw,
    u16* __restrict__ Hout16, float* __restrict__ as_o, float* __restrict__ ad_o)
{
    constexpr int CG = OUTC / 4;     // 32 or 8
    constexpr int RG = 256 / CG;     // 8 or 32
    constexpr int TR = 64 / RG;      // 8 or 2
    __shared__ float Xs[64 * 132];   // 33.8 KB (reused as out-tile for epilogue)
    __shared__ float Wt[32 * OUTC];  // [k][c] per 32-k chunk

    const int tid = threadIdx.x;
    const int r0 = blockIdx.x * 64;
    for (int i = tid; i < 64 * 32; i += 256) {
        int r = i >> 5, kk = (i & 31) << 2;
        float4 v = make_float4(0.f, 0.f, 0.f, 0.f);
        if (r0 + r < NN) v = *(const float4*)(X + (size_t)(r0 + r) * 128 + kk);
        *(float4*)&Xs[r * 132 + kk] = v;
    }
    const int cg = tid % CG;
    const int rg = tid / CG;
    float acc[TR][4];
    #pragma unroll
    for (int r = 0; r < TR; r++)
        #pragma unroll
        for (int j = 0; j < 4; j++) acc[r][j] = 0.f;

    for (int kc = 0; kc < 4; kc++) {
        __syncthreads();
        for (int i = tid; i < 32 * OUTC / 4; i += 256)
            *(float4*)&Wt[i * 4] = *(const float4*)(W + kc * 32 * OUTC + i * 4);
        __syncthreads();
        #pragma unroll
        for (int k0 = 0; k0 < 32; k0 += 4) {
            float4 xv[TR];
            #pragma unroll
            for (int r = 0; r < TR; r++)
                xv[r] = *(const float4*)&Xs[(rg * TR + r) * 132 + kc * 32 + k0];
            #pragma unroll
            for (int j = 0; j < 4; j++) {
                const int c = cg + CG * j;
                float w0 = Wt[(k0 + 0) * OUTC + c];
                float w1 = Wt[(k0 + 1) * OUTC + c];
                float w2 = Wt[(k0 + 2) * OUTC + c];
                float w3 = Wt[(k0 + 3) * OUTC + c];
                #pragma unroll
                for (int r = 0; r < TR; r++)
                    acc[r][j] += xv[r].x * w0 + xv[r].y * w1 + xv[r].z * w2 + xv[r].w * w3;
            }
        }
    }
    // bf16 h store
    #pragma unroll
    for (int r = 0; r < TR; r++) {
        const int row = r0 + rg * TR + r;
        if (row < NN) {
            #pragma unroll
            for (int j = 0; j < 4; j++)
                Hout16[(size_t)row * OUTC + cg + CG * j] = f2bf(acc[r][j]);
        }
    }
    // fused attn epilogue: spill fp32 acc tile to LDS, dot with a_src/a_dst
    __syncthreads();   // all Xs reads done
    if (OUTC == 128) {
        #pragma unroll
        for (int r = 0; r < TR; r++)
            #pragma unroll
            for (int j = 0; j < 4; j++)
                Xs[(rg * TR + r) * 132 + cg + 32 * j] = acc[r][j];
        __syncthreads();
        const int row = tid >> 2, part = tid & 3;   // 4 heads per row
        const float* hp = &Xs[row * 132 + part * 32];
        const float* aw = asw + part * 32;
        const float* dw = adw + part * 32;
        float s = 0.f, d = 0.f;
        #pragma unroll
        for (int c = 0; c < 32; c++) { float hv = hp[c]; s += hv * aw[c]; d += hv * dw[c]; }
        const int grow = r0 + row;
        if (grow < NN) { as_o[(size_t)grow * 4 + part] = s; ad_o[(size_t)grow * 4 + part] = d; }
    } else {
        #pragma unroll
        for (int r = 0; r < TR; r++)
            #pragma unroll
            for (int j = 0; j < 4; j++)
                Xs[(rg * TR + r) * 36 + cg + 8 * j] = acc[r][j];
        __syncthreads();
        if (tid < 64) {
            const float* hp = &Xs[tid * 36];
            float s = 0.f, d = 0.f;
            #pragma unroll
            for (int c = 0; c < 32; c++) { float hv = hp[c]; s += hv * asw[c]; d += hv * adw[c]; }
            const int grow = r0 + tid;
            if (grow < NN) { as_o[grow] = s; ad_o[grow] = d; }
        }
    }
}

// ---------------- CSR build ----------------
__global__ __launch_bounds__(256) void count_kernel(const int* __restrict__ ei, int* __restrict__ deg)
{
    int e = blockIdx.x * 256 + threadIdx.x;
    if (e >= ET) return;
    int s, d; get_edge(ei, e, s, d);
    atomicAdd(&deg[d], 1);
}

__global__ __launch_bounds__(256) void scan1_kernel(const int* __restrict__ deg,
    int* __restrict__ rowp, int* __restrict__ bsum)
{
    __shared__ int lds[256];
    const int t = threadIdx.x;
    const int base = blockIdx.x * 1024 + t * 4;
    int v0 = (base + 0 < NN) ? deg[base + 0] : 0;
    int v1 = (base + 1 < NN) ? deg[base + 1] : 0;
    int v2 = (base + 2 < NN) ? deg[base + 2] : 0;
    int v3 = (base + 3 < NN) ? deg[base + 3] : 0;
    int local = v0 + v1 + v2 + v3;
    lds[t] = local;
    __syncthreads();
    for (int off = 1; off < 256; off <<= 1) {
        int x = (t >= off) ? lds[t - off] : 0;
        __syncthreads();
        lds[t] += x;
        __syncthreads();
    }
    int excl = lds[t] - local;
    if (base + 0 < NN) rowp[base + 0] = excl;
    if (base + 1 < NN) rowp[base + 1] = excl + v0;
    if (base + 2 < NN) rowp[base + 2] = excl + v0 + v1;
    if (base + 3 < NN) rowp[base + 3] = excl + v0 + v1 + v2;
    if (t == 255) bsum[blockIdx.x] = lds[255];
}

__global__ __launch_bounds__(128) void scan2_kernel(int* __restrict__ bsum)
{
    __shared__ int lds[128];
    const int t = threadIdx.x;
    int v = (t < NB_SCAN) ? bsum[t] : 0;
    lds[t] = v;
    __syncthreads();
    for (int off = 1; off < 128; off <<= 1) {
        int x = (t >= off) ? lds[t - off] : 0;
        __syncthreads();
        lds[t] += x;
        __syncthreads();
    }
    if (t < NB_SCAN) bsum[t] = lds[t] - v;
}

__global__ __launch_bounds__(256) void scan3_kernel(int* __restrict__ rowp,
    const int* __restrict__ bsum, int* __restrict__ cursor)
{
    int i = blockIdx.x * 256 + threadIdx.x;
    if (i == 0) rowp[NN] = ET;
    if (i >= NN) return;
    int r = rowp[i] + bsum[i >> 10];
    rowp[i] = r;
    cursor[i] = r;
}

__global__ __launch_bounds__(256) void fill_kernel(const int* __restrict__ ei,
    int* __restrict__ cursor, int* __restrict__ col)
{
    int e = blockIdx.x * 256 + threadIdx.x;
    if (e >= ET) return;
    int s, d; get_edge(ei, e, s, d);
    int pos = atomicAdd(&cursor[d], 1);
    col[pos] = s;
}

// ---------------- fused online-softmax aggregation, H=4: ONE WAVE per node.
// lane owns channels (2l, 2l+1) of head l>>4; 16-edge chunks; gather is one
// u32 load per lane per edge (256 B/wave), 16-deep explicit load pipeline.
template<bool DOELU>
__global__ __launch_bounds__(256) void agg4_kernel(
    const int* __restrict__ rowp, const int* __restrict__ col,
    const float* __restrict__ as_, const float* __restrict__ ad_,
    const u16* __restrict__ Hb16, const float* __restrict__ bias,
    float* __restrict__ outp)
{
    const int lane = threadIdx.x & 63;
    const int node = blockIdx.x * 4 + (threadIdx.x >> 6);
    const int sub = lane & 15;
    const int h = lane >> 4;

    const int start = rowp[node];
    const int end   = rowp[node + 1];
    const float adv = ad_[(size_t)node * 4 + h];
    const char* hbase = (const char*)Hb16 + lane * 4;
    const float2 bv = *(const float2*)(bias + lane * 2);

    float m = -1e30f, den = 0.f, a0 = 0.f, a1 = 0.f;
    for (int j0 = start; j0 < end; j0 += 16) {
        const int j = j0 + sub;
        const bool valid = (j < end);
        const int s = valid ? col[j] : 0;
        const float lg = valid ? leaky(as_[(size_t)s * 4 + h] + adv) : -1e30f;
        float cm = lg;
        #pragma unroll
        for (int off = 8; off; off >>= 1) cm = fmaxf(cm, __shfl_xor(cm, off));
        const float mnew = fmaxf(m, cm);
        const float sc = __expf(m - mnew);
        a0 *= sc; a1 *= sc; den *= sc; m = mnew;
        const float p = valid ? __expf(lg - m) : 0.f;
        float ps = p;
        #pragma unroll
        for (int off = 8; off; off >>= 1) ps += __shfl_xor(ps, off);
        den += ps;
        const int soff = s << 8;   // row byte offset (128 ch * 2 B)
        const int cnt = end - j0;
        if (cnt >= 16) {
            int so[16]; float pi[16];
            #pragma unroll
            for (int i = 0; i < 16; i++) {
                so[i] = __shfl(soff, i);
                pi[i] = __shfl(p, (h << 4) | i);
            }
            #pragma unroll
            for (int i = 0; i < 16; i++) {
                u32 w = *(const u32*)(hbase + so[i]);
                a0 += pi[i] * bf2f(w & 0xffffu);
                a1 += pi[i] * bf2f(w >> 16);
            }
        } else {
            for (int i = 0; i < cnt; i++) {
                int so = __shfl(soff, i);
                float pi = __shfl(p, (h << 4) | i);
                u32 w = *(const u32*)(hbase + so);
                a0 += pi * bf2f(w & 0xffffu);
                a1 += pi * bf2f(w >> 16);
            }
        }
    }
    const float rden = 1.f / (den + 1e-16f);
    float v0 = a0 * rden + bv.x;
    float v1 = a1 * rden + bv.y;
    if (DOELU) {
        v0 = v0 > 0.f ? v0 : (__expf(v0) - 1.f);
        v1 = v1 > 0.f ? v1 : (__expf(v1) - 1.f);
    }
    *(float2*)(outp + (size_t)node * 128 + lane * 2) = make_float2(v0, v1);
}

// ---------------- H=1 (F=32): 32 lanes per node, 32-edge chunks, u16 gather.
__global__ __launch_bounds__(256) void agg1_kernel(
    const int* __restrict__ rowp, const int* __restrict__ col,
    const float* __restrict__ as_, const float* __restrict__ ad_,
    const u16* __restrict__ Hb16, const float* __restrict__ bias,
    float* __restrict__ outp)
{
    const int t = threadIdx.x;
    const int lane = t & 31;
    const int node = blockIdx.x * 8 + (t >> 5);

    const int start = rowp[node];
    const int end   = rowp[node + 1];
    const float adv = ad_[node];
    const char* hbase = (const char*)Hb16 + lane * 2;
    const float bvv = bias[lane];

    float m = -1e30f, den = 0.f, acc = 0.f;
    for (int j0 = start; j0 < end; j0 += 32) {
        const int j = j0 + lane;
        const bool valid = (j < end);
        const int s = valid ? col[j] : 0;
        const float lg = valid ? leaky(as_[s] + adv) : -1e30f;
        float cm = lg;
        #pragma unroll
        for (int off = 16; off; off >>= 1) cm = fmaxf(cm, __shfl_xor(cm, off, 32));
        const float mnew = fmaxf(m, cm);
        const float sc = __expf(m - mnew);
        acc *= sc; den *= sc; m = mnew;
        const float p = valid ? __expf(lg - m) : 0.f;
        float ps = p;
        #pragma unroll
        for (int off = 16; off; off >>= 1) ps += __shfl_xor(ps, off, 32);
        den += ps;
        const int soff = s << 6;   // 32 ch * 2 B
        const int cnt = end - j0;
        if (cnt >= 32) {
            int so[32]; float pi[32];
            #pragma unroll
            for (int i = 0; i < 32; i++) {
                so[i] = __shfl(soff, i, 32);
                pi[i] = __shfl(p, i, 32);
            }
            #pragma unroll
            for (int i = 0; i < 32; i++)
                acc += pi[i] * bf2f((u32)*(const u16*)(hbase + so[i]));
        } else {
            for (int i = 0; i < cnt; i++) {
                int so = __shfl(soff, i, 32);
                float pi = __shfl(p, i, 32);
                acc += pi * bf2f((u32)*(const u16*)(hbase + so));
            }
        }
    }
    outp[(size_t)node * 32 + lane] = acc / (den + 1e-16f) + bvv;
}

extern "C" void kernel_launch(void* const* d_in, const int* in_sizes, int n_in,
                              void* d_out, int out_size, void* d_ws, size_t ws_size,
                              hipStream_t stream)
{
    const float* x   = (const float*)d_in[0];
    const int*   ei  = (const int*)d_in[1];
    const float* W1  = (const float*)d_in[2];
    const float* as1 = (const float*)d_in[3];
    const float* ad1 = (const float*)d_in[4];
    const float* b1  = (const float*)d_in[5];
    const float* W2  = (const float*)d_in[6];
    const float* as2 = (const float*)d_in[7];
    const float* ad2 = (const float*)d_in[8];
    const float* b2  = (const float*)d_in[9];
    const float* W3  = (const float*)d_in[10];
    const float* as3 = (const float*)d_in[11];
    const float* ad3 = (const float*)d_in[12];
    const float* b3  = (const float*)d_in[13];
    float* outp = (float*)d_out;

    char* ws = (char*)d_ws;
    float* xbuf  = (float*)(ws);                  // N*128 f32 = 51.2 MB (agg out / gemm in)
    u16*   hb16  = (u16*)(ws + 51300000);         // N*128 bf16 = 25.6 MB
    u16*   h3b16 = (u16*)(ws + 77000000);         // N*32 bf16 = 6.4 MB
    float* asb   = (float*)(ws + 83500000);       // N*4 f32
    float* adb   = (float*)(ws + 85100000);       // N*4 f32
    int*   deg   = (int*)(ws + 86700000);
    int*   rowp  = (int*)(ws + 87100000);
    int*   cursor= (int*)(ws + 87500016);
    int*   col   = (int*)(ws + 87900032);         // 6.8 MB
    int*   bsum  = (int*)(ws + 94700032);         // total ~94.7 MB

    const dim3 B(256);
    const int gN = (NN + 255) / 256;
    const int gE = (ET + 255) / 256;
    const int gG = (NN + 63) / 64;   // 1563

    // ---------------- CSR build (shared by all layers)
    hipMemsetAsync(deg, 0, (size_t)NN * 4, stream);
    count_kernel<<<gE, B, 0, stream>>>(ei, deg);
    scan1_kernel<<<NB_SCAN, B, 0, stream>>>(deg, rowp, bsum);
    scan2_kernel<<<1, dim3(128), 0, stream>>>(bsum);
    scan3_kernel<<<gN, B, 0, stream>>>(rowp, bsum, cursor);
    fill_kernel<<<gE, B, 0, stream>>>(ei, cursor, col);

    // ---------------- layer 1 (H=4)
    gemm_kernel<128><<<gG, B, 0, stream>>>(x, W1, as1, ad1, hb16, asb, adb);
    agg4_kernel<true><<<NN / 4, B, 0, stream>>>(rowp, col, asb, adb, hb16, b1, xbuf);

    // ---------------- layer 2 (H=4)
    gemm_kernel<128><<<gG, B, 0, stream>>>(xbuf, W2, as2, ad2, hb16, asb, adb);
    agg4_kernel<true><<<NN / 4, B, 0, stream>>>(rowp, col, asb, adb, hb16, b2, xbuf);

    // ---------------- layer 3 (H=1, C=32)
    gemm_kernel<32><<<gG, B, 0, stream>>>(xbuf, W3, as3, ad3, h3b16, asb, adb);
    agg1_kernel<<<NN / 8, B, 0, stream>>>(rowp, col, asb, adb, h3b16, b3, outp);
}

// Round 6
// 749.237 us; speedup vs baseline: 4.7716x; 1.2032x over previous
//
#include <hip/hip_runtime.h>
#include <cstdint>

#define NN 100000
#define EE 1600000
#define ET (EE + NN)
#define NBUCK 782            // ceil(NN/128), 128 nodes per bucket
#define BCAP 3584            // max edges per bucket (mean ~2176, sd ~47)

typedef unsigned int u32;
typedef unsigned short u16;

__device__ __forceinline__ u16 f2bf(float f) {
    union { float f; u32 i; } v; v.f = f;
    u32 r = v.i + 0x7FFFu + ((v.i >> 16) & 1u);
    return (u16)(r >> 16);
}
__device__ __forceinline__ float bf2f(u32 u) {
    union { u32 i; float f; } v; v.i = u << 16; return v.f;
}
__device__ __forceinline__ void get_edge(const int* __restrict__ ei, int e, int& s, int& d) {
    if (e < EE) { s = ei[e]; d = ei[EE + e]; }
    else { s = e - EE; d = s; }
}
__device__ __forceinline__ float leaky(float x) { return x > 0.f ? x : 0.2f * x; }

// ---------------- GEMM + fused attn epilogue (unchanged from round 5)
template<int OUTC>
__global__ __launch_bounds__(256) void gemm_kernel(
    const float* __restrict__ X, const float* __restrict__ W,
    const float* __restrict__ asw, const float* __restrict__ adw,
    u16* __restrict__ Hout16, float* __restrict__ as_o, float* __restrict__ ad_o)
{
    constexpr int CG = OUTC / 4;
    constexpr int RG = 256 / CG;
    constexpr int TR = 64 / RG;
    __shared__ float Xs[64 * 132];
    __shared__ float Wt[32 * OUTC];

    const int tid = threadIdx.x;
    const int r0 = blockIdx.x * 64;
    for (int i = tid; i < 64 * 32; i += 256) {
        int r = i >> 5, kk = (i & 31) << 2;
        float4 v = make_float4(0.f, 0.f, 0.f, 0.f);
        if (r0 + r < NN) v = *(const float4*)(X + (size_t)(r0 + r) * 128 + kk);
        *(float4*)&Xs[r * 132 + kk] = v;
    }
    const int cg = tid % CG;
    const int rg = tid / CG;
    float acc[TR][4];
    #pragma unroll
    for (int r = 0; r < TR; r++)
        #pragma unroll
        for (int j = 0; j < 4; j++) acc[r][j] = 0.f;

    for (int kc = 0; kc < 4; kc++) {
        __syncthreads();
        for (int i = tid; i < 32 * OUTC / 4; i += 256)
            *(float4*)&Wt[i * 4] = *(const float4*)(W + kc * 32 * OUTC + i * 4);
        __syncthreads();
        #pragma unroll
        for (int k0 = 0; k0 < 32; k0 += 4) {
            float4 xv[TR];
            #pragma unroll
            for (int r = 0; r < TR; r++)
                xv[r] = *(const float4*)&Xs[(rg * TR + r) * 132 + kc * 32 + k0];
            #pragma unroll
            for (int j = 0; j < 4; j++) {
                const int c = cg + CG * j;
                float w0 = Wt[(k0 + 0) * OUTC + c];
                float w1 = Wt[(k0 + 1) * OUTC + c];
                float w2 = Wt[(k0 + 2) * OUTC + c];
                float w3 = Wt[(k0 + 3) * OUTC + c];
                #pragma unroll
                for (int r = 0; r < TR; r++)
                    acc[r][j] += xv[r].x * w0 + xv[r].y * w1 + xv[r].z * w2 + xv[r].w * w3;
            }
        }
    }
    #pragma unroll
    for (int r = 0; r < TR; r++) {
        const int row = r0 + rg * TR + r;
        if (row < NN) {
            #pragma unroll
            for (int j = 0; j < 4; j++)
                Hout16[(size_t)row * OUTC + cg + CG * j] = f2bf(acc[r][j]);
        }
    }
    __syncthreads();
    if (OUTC == 128) {
        #pragma unroll
        for (int r = 0; r < TR; r++)
            #pragma unroll
            for (int j = 0; j < 4; j++)
                Xs[(rg * TR + r) * 132 + cg + 32 * j] = acc[r][j];
        __syncthreads();
        const int row = tid >> 2, part = tid & 3;
        const float* hp = &Xs[row * 132 + part * 32];
        const float* aw = asw + part * 32;
        const float* dw = adw + part * 32;
        float s = 0.f, d = 0.f;
        #pragma unroll
        for (int c = 0; c < 32; c++) { float hv = hp[c]; s += hv * aw[c]; d += hv * dw[c]; }
        const int grow = r0 + row;
        if (grow < NN) { as_o[(size_t)grow * 4 + part] = s; ad_o[(size_t)grow * 4 + part] = d; }
    } else {
        #pragma unroll
        for (int r = 0; r < TR; r++)
            #pragma unroll
            for (int j = 0; j < 4; j++)
                Xs[(rg * TR + r) * 36 + cg + 8 * j] = acc[r][j];
        __syncthreads();
        if (tid < 64) {
            const float* hp = &Xs[tid * 36];
            float s = 0.f, d = 0.f;
            #pragma unroll
            for (int c = 0; c < 32; c++) { float hv = hp[c]; s += hv * asw[c]; d += hv * adw[c]; }
            const int grow = r0 + tid;
            if (grow < NN) { as_o[grow] = s; ad_o[grow] = d; }
        }
    }
}

// ---------------- bucketed CSR build ----------------
// bucket b = dst >> 7 holds nodes [b*128, b*128+128). pairs entry: (dst&127)<<25 | src.

__global__ __launch_bounds__(256) void bin_count_kernel(const int* __restrict__ ei,
    int* __restrict__ bcount)
{
    __shared__ int hist[NBUCK];
    const int t = threadIdx.x;
    for (int i = t; i < NBUCK; i += 256) hist[i] = 0;
    __syncthreads();
    const int chunk = (ET + gridDim.x - 1) / gridDim.x;
    const int e0 = blockIdx.x * chunk;
    const int e1 = min(e0 + chunk, ET);
    for (int e = e0 + t; e < e1; e += 256) {
        int s, d; get_edge(ei, e, s, d);
        atomicAdd(&hist[d >> 7], 1);
    }
    __syncthreads();
    for (int i = t; i < NBUCK; i += 256)
        if (hist[i]) atomicAdd(&bcount[i], hist[i]);
}

__global__ __launch_bounds__(1024) void bscan_kernel(const int* __restrict__ bcount,
    int* __restrict__ bbase, int* __restrict__ gcur, int* __restrict__ rowp)
{
    __shared__ int lds[1024];
    const int t = threadIdx.x;
    int v = (t < NBUCK) ? bcount[t] : 0;
    lds[t] = v;
    __syncthreads();
    for (int off = 1; off < 1024; off <<= 1) {
        int x = (t >= off) ? lds[t - off] : 0;
        __syncthreads();
        lds[t] += x;
        __syncthreads();
    }
    if (t < NBUCK) { int ex = lds[t] - v; bbase[t] = ex; gcur[t] = ex; }
    if (t == 0) { bbase[NBUCK] = ET; rowp[NN] = ET; }
}

__global__ __launch_bounds__(256) void bin_fill_kernel(const int* __restrict__ ei,
    int* __restrict__ gcur, u32* __restrict__ pairs)
{
    __shared__ int hist[NBUCK];
    __shared__ int base[NBUCK];
    const int t = threadIdx.x;
    for (int i = t; i < NBUCK; i += 256) hist[i] = 0;
    __syncthreads();
    const int chunk = (ET + gridDim.x - 1) / gridDim.x;
    const int e0 = blockIdx.x * chunk;
    const int e1 = min(e0 + chunk, ET);
    for (int e = e0 + t; e < e1; e += 256) {
        int s, d; get_edge(ei, e, s, d);
        atomicAdd(&hist[d >> 7], 1);
    }
    __syncthreads();
    for (int i = t; i < NBUCK; i += 256) {
        int c = hist[i];
        base[i] = c ? atomicAdd(&gcur[i], c) : 0;
        hist[i] = 0;
    }
    __syncthreads();
    for (int e = e0 + t; e < e1; e += 256) {
        int s, d; get_edge(ei, e, s, d);
        int b = d >> 7;
        int pos = atomicAdd(&hist[b], 1);
        pairs[base[b] + pos] = ((u32)(d & 127) << 25) | (u32)s;
    }
}

__global__ __launch_bounds__(256) void bucket_csr_kernel(const u32* __restrict__ pairs,
    const int* __restrict__ bbase, int* __restrict__ rowp, int* __restrict__ col)
{
    __shared__ int hist[128], scn[128];
    __shared__ int col_lds[BCAP];
    const int b = blockIdx.x;
    const int cbase = bbase[b];
    const int cnt = bbase[b + 1] - cbase;
    const int t = threadIdx.x;
    if (t < 128) hist[t] = 0;
    __syncthreads();
    for (int i = t; i < cnt; i += 256)
        atomicAdd(&hist[pairs[cbase + i] >> 25], 1);
    __syncthreads();
    if (t < 128) scn[t] = hist[t];
    __syncthreads();
    for (int off = 1; off < 128; off <<= 1) {
        int x = (t < 128 && t >= off) ? scn[t - off] : 0;
        __syncthreads();
        if (t < 128) scn[t] += x;
        __syncthreads();
    }
    if (t < 128) {
        int ex = scn[t] - hist[t];
        int node = b * 128 + t;
        if (node < NN) rowp[node] = cbase + ex;
        hist[t] = ex;       // reuse as within-bucket cursor
    }
    __syncthreads();
    for (int i = t; i < cnt; i += 256) {
        u32 pk = pairs[cbase + i];
        int pos = atomicAdd(&hist[pk >> 25], 1);
        if (pos < BCAP) col_lds[pos] = pk & 0x1FFFFFFu;
    }
    __syncthreads();
    for (int i = t; i < cnt; i += 256)
        col[cbase + i] = col_lds[i];
}

// ---------------- fused online-softmax aggregation (unchanged from round 5)
template<bool DOELU>
__global__ __launch_bounds__(256) void agg4_kernel(
    const int* __restrict__ rowp, const int* __restrict__ col,
    const float* __restrict__ as_, const float* __restrict__ ad_,
    const u16* __restrict__ Hb16, const float* __restrict__ bias,
    float* __restrict__ outp)
{
    const int lane = threadIdx.x & 63;
    const int node = blockIdx.x * 4 + (threadIdx.x >> 6);
    const int sub = lane & 15;
    const int h = lane >> 4;

    const int start = rowp[node];
    const int end   = rowp[node + 1];
    const float adv = ad_[(size_t)node * 4 + h];
    const char* hbase = (const char*)Hb16 + lane * 4;
    const float2 bv = *(const float2*)(bias + lane * 2);

    float m = -1e30f, den = 0.f, a0 = 0.f, a1 = 0.f;
    for (int j0 = start; j0 < end; j0 += 16) {
        const int j = j0 + sub;
        const bool valid = (j < end);
        const int s = valid ? col[j] : 0;
        const float lg = valid ? leaky(as_[(size_t)s * 4 + h] + adv) : -1e30f;
        float cm = lg;
        #pragma unroll
        for (int off = 8; off; off >>= 1) cm = fmaxf(cm, __shfl_xor(cm, off));
        const float mnew = fmaxf(m, cm);
        const float sc = __expf(m - mnew);
        a0 *= sc; a1 *= sc; den *= sc; m = mnew;
        const float p = valid ? __expf(lg - m) : 0.f;
        float ps = p;
        #pragma unroll
        for (int off = 8; off; off >>= 1) ps += __shfl_xor(ps, off);
        den += ps;
        const int soff = s << 8;
        const int cnt = end - j0;
        if (cnt >= 16) {
            int so[16]; float pi[16];
            #pragma unroll
            for (int i = 0; i < 16; i++) {
                so[i] = __shfl(soff, i);
                pi[i] = __shfl(p, (h << 4) | i);
            }
            #pragma unroll
            for (int i = 0; i < 16; i++) {
                u32 w = *(const u32*)(hbase + so[i]);
                a0 += pi[i] * bf2f(w & 0xffffu);
                a1 += pi[i] * bf2f(w >> 16);
            }
        } else {
            for (int i = 0; i < cnt; i++) {
                int so = __shfl(soff, i);
                float pi = __shfl(p, (h << 4) | i);
                u32 w = *(const u32*)(hbase + so);
                a0 += pi * bf2f(w & 0xffffu);
                a1 += pi * bf2f(w >> 16);
            }
        }
    }
    const float rden = 1.f / (den + 1e-16f);
    float v0 = a0 * rden + bv.x;
    float v1 = a1 * rden + bv.y;
    if (DOELU) {
        v0 = v0 > 0.f ? v0 : (__expf(v0) - 1.f);
        v1 = v1 > 0.f ? v1 : (__expf(v1) - 1.f);
    }
    *(float2*)(outp + (size_t)node * 128 + lane * 2) = make_float2(v0, v1);
}

__global__ __launch_bounds__(256) void agg1_kernel(
    const int* __restrict__ rowp, const int* __restrict__ col,
    const float* __restrict__ as_, const float* __restrict__ ad_,
    const u16* __restrict__ Hb16, const float* __restrict__ bias,
    float* __restrict__ outp)
{
    const int t = threadIdx.x;
    const int lane = t & 31;
    const int node = blockIdx.x * 8 + (t >> 5);

    const int start = rowp[node];
    const int end   = rowp[node + 1];
    const float adv = ad_[node];
    const char* hbase = (const char*)Hb16 + lane * 2;
    const float bvv = bias[lane];

    float m = -1e30f, den = 0.f, acc = 0.f;
    for (int j0 = start; j0 < end; j0 += 32) {
        const int j = j0 + lane;
        const bool valid = (j < end);
        const int s = valid ? col[j] : 0;
        const float lg = valid ? leaky(as_[s] + adv) : -1e30f;
        float cm = lg;
        #pragma unroll
        for (int off = 16; off; off >>= 1) cm = fmaxf(cm, __shfl_xor(cm, off, 32));
        const float mnew = fmaxf(m, cm);
        const float sc = __expf(m - mnew);
        acc *= sc; den *= sc; m = mnew;
        const float p = valid ? __expf(lg - m) : 0.f;
        float ps = p;
        #pragma unroll
        for (int off = 16; off; off >>= 1) ps += __shfl_xor(ps, off, 32);
        den += ps;
        const int soff = s << 6;
        const int cnt = end - j0;
        if (cnt >= 32) {
            int so[32]; float pi[32];
            #pragma unroll
            for (int i = 0; i < 32; i++) {
                so[i] = __shfl(soff, i, 32);
                pi[i] = __shfl(p, i, 32);
            }
            #pragma unroll
            for (int i = 0; i < 32; i++)
                acc += pi[i] * bf2f((u32)*(const u16*)(hbase + so[i]));
        } else {
            for (int i = 0; i < cnt; i++) {
                int so = __shfl(soff, i, 32);
                float pi = __shfl(p, i, 32);
                acc += pi * bf2f((u32)*(const u16*)(hbase + so));
            }
        }
    }
    outp[(size_t)node * 32 + lane] = acc / (den + 1e-16f) + bvv;
}

extern "C" void kernel_launch(void* const* d_in, const int* in_sizes, int n_in,
                              void* d_out, int out_size, void* d_ws, size_t ws_size,
                              hipStream_t stream)
{
    const float* x   = (const float*)d_in[0];
    const int*   ei  = (const int*)d_in[1];
    const float* W1  = (const float*)d_in[2];
    const float* as1 = (const float*)d_in[3];
    const float* ad1 = (const float*)d_in[4];
    const float* b1  = (const float*)d_in[5];
    const float* W2  = (const float*)d_in[6];
    const float* as2 = (const float*)d_in[7];
    const float* ad2 = (const float*)d_in[8];
    const float* b2  = (const float*)d_in[9];
    const float* W3  = (const float*)d_in[10];
    const float* as3 = (const float*)d_in[11];
    const float* ad3 = (const float*)d_in[12];
    const float* b3  = (const float*)d_in[13];
    float* outp = (float*)d_out;

    char* ws = (char*)d_ws;
    float* xbuf  = (float*)(ws);                  // N*128 f32 = 51.2 MB
    u16*   hb16  = (u16*)(ws + 51300000);         // N*128 bf16 = 25.6 MB
    u16*   h3b16 = (u16*)(ws + 77000000);         // N*32 bf16 = 6.4 MB
    float* asb   = (float*)(ws + 83500000);       // N*4 f32
    float* adb   = (float*)(ws + 85100000);       // N*4 f32
    int*   rowp  = (int*)(ws + 86700000);         // N+1 ints
    int*   col   = (int*)(ws + 87200000);         // ET ints = 6.8 MB
    u32*   pairs = (u32*)(ws + 94000032);         // ET u32 = 6.8 MB
    int*   bcount= (int*)(ws + 100800064);        // NBUCK ints
    int*   bbase = (int*)(ws + 100804160);        // NBUCK+1 ints
    int*   gcur  = (int*)(ws + 100808256);        // NBUCK ints -> ~100.9 MB total

    const dim3 B(256);
    const int gG = (NN + 63) / 64;   // 1563

    // ---------------- bucketed CSR build (shared by all layers)
    hipMemsetAsync(bcount, 0, NBUCK * 4, stream);
    bin_count_kernel<<<256, B, 0, stream>>>(ei, bcount);
    bscan_kernel<<<1, dim3(1024), 0, stream>>>(bcount, bbase, gcur, rowp);
    bin_fill_kernel<<<256, B, 0, stream>>>(ei, gcur, pairs);
    bucket_csr_kernel<<<NBUCK, B, 0, stream>>>(pairs, bbase, rowp, col);

    // ---------------- layer 1 (H=4)
    gemm_kernel<128><<<gG, B, 0, stream>>>(x, W1, as1, ad1, hb16, asb, adb);
    agg4_kernel<true><<<NN / 4, B, 0, stream>>>(rowp, col, asb, adb, hb16, b1, xbuf);

    // ---------------- layer 2 (H=4)
    gemm_kernel<128><<<gG, B, 0, stream>>>(xbuf, W2, as2, ad2, hb16, asb, adb);
    agg4_kernel<true><<<NN / 4, B, 0, stream>>>(rowp, col, asb, adb, hb16, b2, xbuf);

    // ---------------- layer 3 (H=1, C=32)
    gemm_kernel<32><<<gG, B, 0, stream>>>(xbuf, W3, as3, ad3, h3b16, asb, adb);
    agg1_kernel<<<NN / 8, B, 0, stream>>>(rowp, col, asb, adb, h3b16, b3, outp);
}